// Round 13
// baseline (214.638 us; speedup 1.0000x reference)
//
#include <hip/hip_runtime.h>
#include <hip/hip_bf16.h>

#define BB 64
#define NN 512
#define DIN 33
#define DD 32
#define EE 8192
#define NHEADS 4
#define DH 8
#define FFD 64

typedef __attribute__((ext_vector_type(4))) float f32x4;
typedef __attribute__((ext_vector_type(4))) short bf16x4;

static __device__ __forceinline__ short f2bf(float x) {
    unsigned u = __float_as_uint(x);
    u = (u + 0x7FFFu + ((u >> 16) & 1u)) >> 16;
    return (short)u;
}

static __device__ __forceinline__ unsigned pack_trunc(float a, float b) {
    return (__float_as_uint(a) >> 16) | (__float_as_uint(b) & 0xFFFF0000u);
}

static __device__ __forceinline__ void mfma16(f32x4& d, bf16x4 a, bf16x4 b) {
#if __has_builtin(__builtin_amdgcn_mfma_f32_16x16x16bf16_1k)
    d = __builtin_amdgcn_mfma_f32_16x16x16bf16_1k(a, b, d, 0, 0, 0);
#else
    asm volatile("s_nop 1\n\tv_mfma_f32_16x16x16_bf16 %0, %1, %2, %0\n\ts_nop 7"
                 : "+v"(d) : "v"(a), "v"(b));
#endif
}

// ---------------------------------------------------------------------------
// Embedding (blocks 0..511, 64 nodes each, shuffle-based) + CSR (block 512,
// 8-deep batched edge processing for latency hiding).
// ---------------------------------------------------------------------------
__global__ __launch_bounds__(256) void k_embcsr(const float* __restrict__ H,
                                                const float* __restrict__ W1, const float* __restrict__ b1,
                                                const float* __restrict__ W2, const float* __restrict__ b2,
                                                const float* __restrict__ g,  const float* __restrict__ be,
                                                float* __restrict__ xb, float* __restrict__ xt,
                                                const int* __restrict__ ei,
                                                float* __restrict__ cnt_f,
                                                int* __restrict__ csr_off,
                                                int* __restrict__ csr_src,
                                                float* __restrict__ stats) {
    __shared__ float sW1[DIN * DD];
    __shared__ float sW2[DD * DD];
    __shared__ float sb1[DD], sb2[DD], sg[DD], sbe[DD];
    __shared__ int cnt_s[NN];
    __shared__ int wsum[4];
    int tid = threadIdx.x;
    if (blockIdx.x == 512) {
        // ---- CSR path (batched 8-deep) ----
        cnt_s[tid] = 0; cnt_s[tid + 256] = 0;
        stats[tid] = 0.f;   // [2 layers][bn1|bn2][sum|sumsq][32]
        __syncthreads();
        const int* src = ei;
        const int* dst = ei + EE;
        #pragma unroll
        for (int r = 0; r < 4; ++r) {
            int base = r * 2048 + tid * 8;
            int4 d0 = *(const int4*)&dst[base];
            int4 d1 = *(const int4*)&dst[base + 4];
            atomicAdd(&cnt_s[d0.x], 1); atomicAdd(&cnt_s[d0.y], 1);
            atomicAdd(&cnt_s[d0.z], 1); atomicAdd(&cnt_s[d0.w], 1);
            atomicAdd(&cnt_s[d1.x], 1); atomicAdd(&cnt_s[d1.y], 1);
            atomicAdd(&cnt_s[d1.z], 1); atomicAdd(&cnt_s[d1.w], 1);
        }
        __syncthreads();
        int c0 = cnt_s[2 * tid], c1 = cnt_s[2 * tid + 1];
        int cp = c0 + c1;
        int lane = tid & 63, w = tid >> 6;
        int sc = cp;
        #pragma unroll
        for (int off = 1; off < 64; off <<= 1) {
            int v = __shfl_up(sc, off, 64);
            if (lane >= off) sc += v;
        }
        if (lane == 63) wsum[w] = sc;
        __syncthreads();
        if (tid == 0) {
            int a = 0;
            #pragma unroll
            for (int i = 0; i < 4; ++i) { int t = wsum[i]; wsum[i] = a; a += t; }
        }
        __syncthreads();
        int excl = sc - cp + wsum[w];
        cnt_f[2 * tid] = (float)c0; cnt_f[2 * tid + 1] = (float)c1;
        csr_off[2 * tid] = excl; csr_off[2 * tid + 1] = excl + c0;
        if (tid == 255) csr_off[NN] = excl + cp;
        __syncthreads();
        cnt_s[2 * tid] = excl; cnt_s[2 * tid + 1] = excl + c0;
        __syncthreads();
        #pragma unroll
        for (int r = 0; r < 4; ++r) {
            int base = r * 2048 + tid * 8;
            int4 d0 = *(const int4*)&dst[base];
            int4 d1 = *(const int4*)&dst[base + 4];
            int4 s0 = *(const int4*)&src[base];
            int4 s1 = *(const int4*)&src[base + 4];
            int p;
            p = atomicAdd(&cnt_s[d0.x], 1); csr_src[p] = s0.x;
            p = atomicAdd(&cnt_s[d0.y], 1); csr_src[p] = s0.y;
            p = atomicAdd(&cnt_s[d0.z], 1); csr_src[p] = s0.z;
            p = atomicAdd(&cnt_s[d0.w], 1); csr_src[p] = s0.w;
            p = atomicAdd(&cnt_s[d1.x], 1); csr_src[p] = s1.x;
            p = atomicAdd(&cnt_s[d1.y], 1); csr_src[p] = s1.y;
            p = atomicAdd(&cnt_s[d1.z], 1); csr_src[p] = s1.z;
            p = atomicAdd(&cnt_s[d1.w], 1); csr_src[p] = s1.w;
        }
        return;
    }
    // ---- Embedding path: 64 nodes per block, 8 per pass, shuffle broadcast ----
    for (int i = tid; i < DIN * DD; i += 256) sW1[i] = W1[i];
    for (int i = tid; i < DD * DD; i += 256) sW2[i] = W2[i];
    if (tid < DD) { sb1[tid] = b1[tid]; sb2[tid] = b2[tid]; sg[tid] = g[tid]; sbe[tid] = be[tid]; }
    __syncthreads();
    int grp = tid >> 5, lane = tid & 31;
    for (int it = 0; it < 8; ++it) {
        size_t node = (size_t)blockIdx.x * 64 + it * 8 + grp;
        const float* hrow = H + node * DIN;
        float hval = hrow[lane];
        float h32  = hrow[32];
        float acc = sb1[lane];
        #pragma unroll
        for (int i = 0; i < 32; ++i) acc += __shfl(hval, i, 32) * sW1[i * DD + lane];
        acc += h32 * sW1[32 * DD + lane];
        acc = fmaxf(acc, 0.f);
        float acc2 = sb2[lane];
        #pragma unroll
        for (int i = 0; i < DD; ++i) acc2 += __shfl(acc, i, 32) * sW2[i * DD + lane];
        acc2 = fmaxf(acc2, 0.f);
        float s = acc2;
        for (int off = 16; off; off >>= 1) s += __shfl_xor(s, off, 32);
        float m = s * (1.f / 32.f);
        float dv = acc2 - m;
        float sq = dv * dv;
        for (int off = 16; off; off >>= 1) sq += __shfl_xor(sq, off, 32);
        float var = sq * (1.f / 32.f);
        float v = dv * rsqrtf(var + 1e-5f) * sg[lane] + sbe[lane];
        xb[node * DD + lane] = v;
        int b = (int)(node >> 9), n = (int)(node & 511);
        xt[(size_t)n * 2048 + b * DD + lane] = v;
    }
}

// ---------------------------------------------------------------------------
// GNN hop 1: RAW gather + post-hoc BN affine (valid since gamma>0) + MFMA.
// ---------------------------------------------------------------------------
__global__ __launch_bounds__(256) void k_gnn1(const float* __restrict__ src, float* __restrict__ ht,
                                              const float* __restrict__ cnt_f,
                                              const int* __restrict__ csr_off,
                                              const int* __restrict__ csr_src,
                                              const float* __restrict__ W, const float* __restrict__ bias,
                                              const float* __restrict__ bnstats,
                                              const float* __restrict__ bng, const float* __restrict__ bnb) {
    __shared__ short conc[32 * 132];
    __shared__ short sWt[32 * 132];
    __shared__ float sb[DD];
    __shared__ float scv[DD], offv[DD];
    int tid = threadIdx.x;
    int n = blockIdx.x >> 1, half = blockIdx.x & 1;
    for (int i = tid; i < 128 * DD; i += 256) {
        int k = i >> 5, d = i & 31;
        sWt[d * 132 + k] = f2bf(W[i]);
    }
    if (tid < DD) {
        sb[tid] = bias[tid];
        if (bnstats) {
            float mean = bnstats[tid] * (1.f / 32768.f);
            float var  = bnstats[DD + tid] * (1.f / 32768.f) - mean * mean;
            float sc = rsqrtf(var + 1e-5f) * bng[tid];
            scv[tid] = sc; offv[tid] = bnb[tid] - mean * sc;
        } else { scv[tid] = 1.f; offv[tid] = 0.f; }
    }
    __syncthreads();
    float4 sc4, of4;
    { int d0 = (tid * 4) & 31;
      sc4.x = scv[d0]; sc4.y = scv[d0 + 1]; sc4.z = scv[d0 + 2]; sc4.w = scv[d0 + 3];
      of4.x = offv[d0]; of4.y = offv[d0 + 1]; of4.z = offv[d0 + 2]; of4.w = offv[d0 + 3]; }
    const float* xbase = src + (size_t)half * 1024 + tid * 4;
    float4 hv = *(const float4*)&xbase[(size_t)n * 2048];
    float4 s = {0.f, 0.f, 0.f, 0.f};
    float4 mx = {-1e30f, -1e30f, -1e30f, -1e30f};
    int beg = csr_off[n], end = csr_off[n + 1];
    int idx = beg;
    for (; idx + 7 < end; idx += 8) {
        float4 v[8];
        #pragma unroll
        for (int j = 0; j < 8; ++j)
            v[j] = *(const float4*)&xbase[(size_t)csr_src[idx + j] * 2048];
        #pragma unroll
        for (int j = 0; j < 8; ++j) {
            s.x += v[j].x; s.y += v[j].y; s.z += v[j].z; s.w += v[j].w;
            mx.x = fmaxf(mx.x, v[j].x); mx.y = fmaxf(mx.y, v[j].y);
            mx.z = fmaxf(mx.z, v[j].z); mx.w = fmaxf(mx.w, v[j].w);
        }
    }
    for (; idx + 3 < end; idx += 4) {
        float4 v[4];
        #pragma unroll
        for (int j = 0; j < 4; ++j)
            v[j] = *(const float4*)&xbase[(size_t)csr_src[idx + j] * 2048];
        #pragma unroll
        for (int j = 0; j < 4; ++j) {
            s.x += v[j].x; s.y += v[j].y; s.z += v[j].z; s.w += v[j].w;
            mx.x = fmaxf(mx.x, v[j].x); mx.y = fmaxf(mx.y, v[j].y);
            mx.z = fmaxf(mx.z, v[j].z); mx.w = fmaxf(mx.w, v[j].w);
        }
    }
    for (; idx < end; ++idx) {
        float4 v0 = *(const float4*)&xbase[(size_t)csr_src[idx] * 2048];
        s.x += v0.x; s.y += v0.y; s.z += v0.z; s.w += v0.w;
        mx.x = fmaxf(mx.x, v0.x); mx.y = fmaxf(mx.y, v0.y);
        mx.z = fmaxf(mx.z, v0.z); mx.w = fmaxf(mx.w, v0.w);
    }
    float c = cnt_f[n];
    float rinv = 1.f / fmaxf(c, 1.f);
    hv.x = fmaf(hv.x, sc4.x, of4.x); hv.y = fmaf(hv.y, sc4.y, of4.y);
    hv.z = fmaf(hv.z, sc4.z, of4.z); hv.w = fmaf(hv.w, sc4.w, of4.w);
    float4 sa;
    sa.x = fmaf(s.x, sc4.x, c * of4.x); sa.y = fmaf(s.y, sc4.y, c * of4.y);
    sa.z = fmaf(s.z, sc4.z, c * of4.z); sa.w = fmaf(s.w, sc4.w, c * of4.w);
    if (c > 0.f) {
        mx.x = fmaf(mx.x, sc4.x, of4.x); mx.y = fmaf(mx.y, sc4.y, of4.y);
        mx.z = fmaf(mx.z, sc4.z, of4.z); mx.w = fmaf(mx.w, sc4.w, of4.w);
    } else { mx.x = 0.f; mx.y = 0.f; mx.z = 0.f; mx.w = 0.f; }
    int bl = tid >> 3, d0 = (tid & 7) * 4;
    short* cp = &conc[bl * 132];
    bf16x4 t;
    t.x = f2bf(hv.x); t.y = f2bf(hv.y); t.z = f2bf(hv.z); t.w = f2bf(hv.w);
    *(bf16x4*)&cp[d0] = t;
    t.x = f2bf(sa.x * rinv); t.y = f2bf(sa.y * rinv); t.z = f2bf(sa.z * rinv); t.w = f2bf(sa.w * rinv);
    *(bf16x4*)&cp[32 + d0] = t;
    t.x = f2bf(mx.x); t.y = f2bf(mx.y); t.z = f2bf(mx.z); t.w = f2bf(mx.w);
    *(bf16x4*)&cp[64 + d0] = t;
    t.x = f2bf(sa.x); t.y = f2bf(sa.y); t.z = f2bf(sa.z); t.w = f2bf(sa.w);
    *(bf16x4*)&cp[96 + d0] = t;
    __syncthreads();
    int wid = tid >> 6, lane = tid & 63;
    int cc = lane & 15, g = lane >> 4;
    int arow = (wid >> 1) * 16 + cc;
    int bcol = (wid & 1) * 16 + cc;
    f32x4 acc = {0.f, 0.f, 0.f, 0.f};
    #pragma unroll
    for (int ks = 0; ks < 8; ++ks) {
        bf16x4 af = *(const bf16x4*)&conc[arow * 132 + ks * 16 + g * 4];
        bf16x4 bfr = *(const bf16x4*)&sWt[bcol * 132 + ks * 16 + g * 4];
        mfma16(acc, af, bfr);
    }
    float bia = sb[bcol];
    int brow = (wid >> 1) * 16 + g * 4;
    float* obase = &ht[(size_t)n * 2048 + half * 1024 + bcol];
    #pragma unroll
    for (int r = 0; r < 4; ++r) {
        obase[(size_t)(brow + r) * DD] = fmaxf(acc[r] + bia, 0.f);
    }
}

// ---------------------------------------------------------------------------
// GNN hop 2 + QKV.  Wq pre-scaled by 1/sqrt(dh)*log2(e) (attn uses exp2f).
// ---------------------------------------------------------------------------
__global__ __launch_bounds__(256) void k_gnn2(const float* __restrict__ hsrc,
                                              const float* __restrict__ cnt_f,
                                              const int* __restrict__ csr_off,
                                              const int* __restrict__ csr_src,
                                              const float* __restrict__ W, const float* __restrict__ bias,
                                              const float* __restrict__ xsrc,
                                              const float* __restrict__ bnstats,
                                              const float* __restrict__ bng, const float* __restrict__ bnb,
                                              const float* __restrict__ Wq, const float* __restrict__ Wk,
                                              const float* __restrict__ Wv,
                                              short* __restrict__ qb2, short* __restrict__ kb2,
                                              short* __restrict__ vb2) {
    __shared__ short conc[32 * 132];
    __shared__ short sWt[32 * 132];
    __shared__ short sWqT[32 * 36], sWkT[32 * 36], sWvT[32 * 36];
    __shared__ short h_lds[32 * 36], x_lds[32 * 36];
    __shared__ float sb[DD];
    __shared__ float scv[DD], offv[DD];
    int tid = threadIdx.x;
    int n = blockIdx.x >> 1, half = blockIdx.x & 1;
    for (int i = tid; i < 128 * DD; i += 256) {
        int k = i >> 5, d = i & 31;
        sWt[d * 132 + k] = f2bf(W[i]);
    }
    {
        const float qsc = 0.35355339059327373f * 1.44269504088896f;  // isq * log2(e)
        for (int i = tid; i < 1024; i += 256) {
            int k = i >> 5, col = i & 31;
            sWqT[col * 36 + k] = f2bf(Wq[i] * qsc);
            sWkT[col * 36 + k] = f2bf(Wk[i]);
            sWvT[col * 36 + k] = f2bf(Wv[i]);
        }
    }
    if (tid < DD) {
        sb[tid] = bias[tid];
        if (bnstats) {
            float mean = bnstats[tid] * (1.f / 32768.f);
            float var  = bnstats[DD + tid] * (1.f / 32768.f) - mean * mean;
            float sc = rsqrtf(var + 1e-5f) * bng[tid];
            scv[tid] = sc; offv[tid] = bnb[tid] - mean * sc;
        } else { scv[tid] = 1.f; offv[tid] = 0.f; }
    }
    __syncthreads();
    {
        int bl = tid >> 3, d0 = (tid & 7) * 4;
        float4 x4 = *(const float4*)&xsrc[(size_t)n * 2048 + half * 1024 + bl * 32 + d0];
        x4.x = fmaf(x4.x, scv[d0], offv[d0]);
        x4.y = fmaf(x4.y, scv[d0 + 1], offv[d0 + 1]);
        x4.z = fmaf(x4.z, scv[d0 + 2], offv[d0 + 2]);
        x4.w = fmaf(x4.w, scv[d0 + 3], offv[d0 + 3]);
        bf16x4 xp; xp.x = f2bf(x4.x); xp.y = f2bf(x4.y); xp.z = f2bf(x4.z); xp.w = f2bf(x4.w);
        *(bf16x4*)&x_lds[bl * 36 + d0] = xp;
    }
    const float* xbase = hsrc + (size_t)half * 1024 + tid * 4;
    float4 hv = *(const float4*)&xbase[(size_t)n * 2048];
    float4 s = {0.f, 0.f, 0.f, 0.f};
    float4 mx = {-1e30f, -1e30f, -1e30f, -1e30f};
    int beg = csr_off[n], end = csr_off[n + 1];
    int idx = beg;
    for (; idx + 7 < end; idx += 8) {
        float4 v[8];
        #pragma unroll
        for (int j = 0; j < 8; ++j)
            v[j] = *(const float4*)&xbase[(size_t)csr_src[idx + j] * 2048];
        #pragma unroll
        for (int j = 0; j < 8; ++j) {
            s.x += v[j].x; s.y += v[j].y; s.z += v[j].z; s.w += v[j].w;
            mx.x = fmaxf(mx.x, v[j].x); mx.y = fmaxf(mx.y, v[j].y);
            mx.z = fmaxf(mx.z, v[j].z); mx.w = fmaxf(mx.w, v[j].w);
        }
    }
    for (; idx + 3 < end; idx += 4) {
        float4 v[4];
        #pragma unroll
        for (int j = 0; j < 4; ++j)
            v[j] = *(const float4*)&xbase[(size_t)csr_src[idx + j] * 2048];
        #pragma unroll
        for (int j = 0; j < 4; ++j) {
            s.x += v[j].x; s.y += v[j].y; s.z += v[j].z; s.w += v[j].w;
            mx.x = fmaxf(mx.x, v[j].x); mx.y = fmaxf(mx.y, v[j].y);
            mx.z = fmaxf(mx.z, v[j].z); mx.w = fmaxf(mx.w, v[j].w);
        }
    }
    for (; idx < end; ++idx) {
        float4 v0 = *(const float4*)&xbase[(size_t)csr_src[idx] * 2048];
        s.x += v0.x; s.y += v0.y; s.z += v0.z; s.w += v0.w;
        mx.x = fmaxf(mx.x, v0.x); mx.y = fmaxf(mx.y, v0.y);
        mx.z = fmaxf(mx.z, v0.z); mx.w = fmaxf(mx.w, v0.w);
    }
    float c = cnt_f[n];
    float rinv = 1.f / fmaxf(c, 1.f);
    if (!(c > 0.f)) { mx.x = 0.f; mx.y = 0.f; mx.z = 0.f; mx.w = 0.f; }
    int bl = tid >> 3, d0 = (tid & 7) * 4;
    short* cp = &conc[bl * 132];
    bf16x4 t;
    t.x = f2bf(hv.x); t.y = f2bf(hv.y); t.z = f2bf(hv.z); t.w = f2bf(hv.w);
    *(bf16x4*)&cp[d0] = t;
    t.x = f2bf(s.x * rinv); t.y = f2bf(s.y * rinv); t.z = f2bf(s.z * rinv); t.w = f2bf(s.w * rinv);
    *(bf16x4*)&cp[32 + d0] = t;
    t.x = f2bf(mx.x); t.y = f2bf(mx.y); t.z = f2bf(mx.z); t.w = f2bf(mx.w);
    *(bf16x4*)&cp[64 + d0] = t;
    t.x = f2bf(s.x); t.y = f2bf(s.y); t.z = f2bf(s.z); t.w = f2bf(s.w);
    *(bf16x4*)&cp[96 + d0] = t;
    __syncthreads();
    int wid = tid >> 6, lane = tid & 63;
    int cc = lane & 15, g = lane >> 4;
    int arow = (wid >> 1) * 16 + cc;
    int bcol = (wid & 1) * 16 + cc;
    f32x4 acc = {0.f, 0.f, 0.f, 0.f};
    #pragma unroll
    for (int ks = 0; ks < 8; ++ks) {
        bf16x4 af = *(const bf16x4*)&conc[arow * 132 + ks * 16 + g * 4];
        bf16x4 bfr = *(const bf16x4*)&sWt[bcol * 132 + ks * 16 + g * 4];
        mfma16(acc, af, bfr);
    }
    float bia = sb[bcol];
    int brow = (wid >> 1) * 16 + g * 4;
    #pragma unroll
    for (int r = 0; r < 4; ++r) {
        h_lds[(brow + r) * 36 + bcol] = f2bf(fmaxf(acc[r] + bia, 0.f));
    }
    __syncthreads();
    int tr = wid >> 1, tc = wid & 1;
    f32x4 qa = {0.f, 0.f, 0.f, 0.f}, ka = qa, va = qa;
    #pragma unroll
    for (int ks = 0; ks < 2; ++ks) {
        bf16x4 ha = *(const bf16x4*)&h_lds[(tr * 16 + cc) * 36 + ks * 16 + g * 4];
        bf16x4 xa = *(const bf16x4*)&x_lds[(tr * 16 + cc) * 36 + ks * 16 + g * 4];
        bf16x4 wq = *(const bf16x4*)&sWqT[(tc * 16 + cc) * 36 + ks * 16 + g * 4];
        bf16x4 wk = *(const bf16x4*)&sWkT[(tc * 16 + cc) * 36 + ks * 16 + g * 4];
        bf16x4 wv = *(const bf16x4*)&sWvT[(tc * 16 + cc) * 36 + ks * 16 + g * 4];
        mfma16(qa, ha, wq);
        mfma16(ka, ha, wk);
        mfma16(va, xa, wv);
    }
    int dcol = tc * 16 + cc;
    size_t base = ((size_t)(half * 32 + tr * 16 + g * 4) * NN + n) * DD + dcol;
    #pragma unroll
    for (int r = 0; r < 4; ++r) {
        size_t p = base + (size_t)r * (NN * DD);
        qb2[p] = f2bf(qa[r]);
        kb2[p] = f2bf(ka[r]);
        vb2[p] = f2bf(va[r]);
    }
}

// ---------------------------------------------------------------------------
// Attention (exp2 softmax, no max) + Wo proj + residual + BN1 stats.
// Grid 1024: block = (b XCD-grouped, 32-q-row slice qs of 16), wave = head,
// 2 q-tiles/wave.  K from global (prefetched), V in LDS.
// ---------------------------------------------------------------------------
__global__ __launch_bounds__(256) void k_attn_proj(const short* __restrict__ qb2,
                                                   const short* __restrict__ kb2,
                                                   const short* __restrict__ vb2,
                                                   const float* __restrict__ x,
                                                   const float* __restrict__ bnstats,
                                                   const float* __restrict__ bng,
                                                   const float* __restrict__ bnb,
                                                   const float* __restrict__ Wo,
                                                   float* __restrict__ t,
                                                   float* __restrict__ stats) {
    __shared__ short Vt[NHEADS * DH * 528];   // [h][d][528] bf16, 33 KB
    __shared__ short Ot[32 * 36];
    __shared__ short sWoT[DD * 36];
    __shared__ float rs[4][DD], rq[4][DD];
    __shared__ float scv[DD], offv[DD];
    int i = blockIdx.x;
    int b = ((i & 7) << 3) | ((i >> 3) & 7);   // XCD-grouped b (b>>3 fixed per XCD slot)
    int qs = i >> 6;                           // 0..15, 32 q-rows each
    int tid = threadIdx.x;

    for (int j = tid; j < 1024; j += 256) {
        int k = j >> 5, col = j & 31;
        sWoT[col * 36 + k] = f2bf(Wo[j]);
    }
    if (tid < DD) {
        if (bnstats) {
            float mean = bnstats[tid] * (1.f / 32768.f);
            float var  = bnstats[DD + tid] * (1.f / 32768.f) - mean * mean;
            float sc = rsqrtf(var + 1e-5f) * bng[tid];
            scv[tid] = sc; offv[tid] = bnb[tid] - mean * sc;
        } else { scv[tid] = 1.f; offv[tid] = 0.f; }
    }
    {
        size_t g0 = ((size_t)b * NN + tid * 2) * DD;
        #pragma unroll
        for (int h2 = 0; h2 < 4; ++h2) {
            uint4 v0 = *(const uint4*)&vb2[g0 + h2 * 8];
            uint4 v1 = *(const uint4*)&vb2[g0 + DD + h2 * 8];
            unsigned* vt = (unsigned*)&Vt[h2 * DH * 528];
            vt[0 * 264 + tid] = (v0.x & 0xFFFFu) | (v1.x << 16);
            vt[1 * 264 + tid] = (v0.x >> 16)     | (v1.x & 0xFFFF0000u);
            vt[2 * 264 + tid] = (v0.y & 0xFFFFu) | (v1.y << 16);
            vt[3 * 264 + tid] = (v0.y >> 16)     | (v1.y & 0xFFFF0000u);
            vt[4 * 264 + tid] = (v0.z & 0xFFFFu) | (v1.z << 16);
            vt[5 * 264 + tid] = (v0.z >> 16)     | (v1.z & 0xFFFF0000u);
            vt[6 * 264 + tid] = (v0.w & 0xFFFFu) | (v1.w << 16);
            vt[7 * 264 + tid] = (v0.w >> 16)     | (v1.w & 0xFFFF0000u);
        }
    }
    __syncthreads();

    int h = tid >> 6, lane = tid & 63;
    int c = lane & 15, g = lane >> 4;
    int c7 = c & 7;
    bf16x4 z4 = {0, 0, 0, 0};
    bf16x4 qf0 = z4, qf1 = z4;
    if (g < 2) {
        const short* qbase = &qb2[(((size_t)b * NN + qs * 32) * DD) + h * DH + g * 4];
        qf0 = *(const bf16x4*)&qbase[(size_t)(c) * DD];
        qf1 = *(const bf16x4*)&qbase[(size_t)(16 + c) * DD];
    }
    const short* kbase = &kb2[((size_t)b * NN) * DD + h * DH + g * 4];
    float l0 = 0.f, l1 = 0.f;
    f32x4 o0 = {0.f, 0.f, 0.f, 0.f}, o1 = o0;
    union U { unsigned u[2]; bf16x4 v4; };

    bf16x4 kf_cur = z4;
    if (g < 2) kf_cur = *(const bf16x4*)&kbase[(size_t)(c) * DD];
    for (int kc = 0; kc < 32; ++kc) {
        bf16x4 kf = kf_cur;
        if (g < 2 && kc < 31)
            kf_cur = *(const bf16x4*)&kbase[(size_t)((kc + 1) * 16 + c) * DD];
        bf16x4 vf = z4;
        {
            bf16x4 vl = *(const bf16x4*)&Vt[(h * DH + c7) * 528 + kc * 16 + g * 4];
            if (c < 8) vf = vl;
        }
        f32x4 st0 = {0.f, 0.f, 0.f, 0.f}, st1 = st0;
        mfma16(st0, kf, qf0);
        mfma16(st1, kf, qf1);
        {
            float p0 = exp2f(st0[0]), p1 = exp2f(st0[1]), p2 = exp2f(st0[2]), p3 = exp2f(st0[3]);
            l0 += (p0 + p1) + (p2 + p3);
            U pu; pu.u[0] = pack_trunc(p0, p1); pu.u[1] = pack_trunc(p2, p3);
            mfma16(o0, vf, pu.v4);
        }
        {
            float p0 = exp2f(st1[0]), p1 = exp2f(st1[1]), p2 = exp2f(st1[2]), p3 = exp2f(st1[3]);
            l1 += (p0 + p1) + (p2 + p3);
            U pu; pu.u[0] = pack_trunc(p0, p1); pu.u[1] = pack_trunc(p2, p3);
            mfma16(o1, vf, pu.v4);
        }
    }
    l0 += __shfl_xor(l0, 16, 64); l0 += __shfl_xor(l0, 32, 64);
    l1 += __shfl_xor(l1, 16, 64); l1 += __shfl_xor(l1, 32, 64);
    if (g < 2) {
        float inv0 = 1.f / l0, inv1 = 1.f / l1;
        int fb = h * DH + g * 4;
        #pragma unroll
        for (int r = 0; r < 4; ++r) {
            Ot[(c) * 36 + fb + r]      = f2bf(o0[r] * inv0);
            Ot[(16 + c) * 36 + fb + r] = f2bf(o1[r] * inv1);
        }
    }
    __syncthreads();
    // epilogue: wave h -> output tile (row-tile tr = h&1, col-tile tc = h>>1)
    int tr = h & 1, tc = h >> 1;
    f32x4 pa = {0.f, 0.f, 0.f, 0.f};
    #pragma unroll
    for (int ks = 0; ks < 2; ++ks) {
        bf16x4 af = *(const bf16x4*)&Ot[(tr * 16 + c) * 36 + ks * 16 + g * 4];
        bf16x4 bw = *(const bf16x4*)&sWoT[(tc * 16 + c) * 36 + ks * 16 + g * 4];
        mfma16(pa, af, bw);
    }
    float scx = scv[tc * 16 + c], ofx = offv[tc * 16 + c];
    float ls = 0.f, lq = 0.f;
    size_t rowbase = ((size_t)b * NN + qs * 32 + tr * 16 + g * 4) * DD;
    #pragma unroll
    for (int r = 0; r < 4; ++r) {
        float xv = fmaf(x[rowbase + (size_t)r * DD + tc * 16 + c], scx, ofx);
        float tv = xv + pa[r];
        t[rowbase + (size_t)r * DD + tc * 16 + c] = tv;
        ls += tv; lq += tv * tv;
    }
    ls += __shfl_xor(ls, 16, 64); ls += __shfl_xor(ls, 32, 64);
    lq += __shfl_xor(lq, 16, 64); lq += __shfl_xor(lq, 32, 64);
    if (g == 0) {
        rs[h][tc * 16 + c] = ls;       rq[h][tc * 16 + c] = lq;
        rs[h][(1 - tc) * 16 + c] = 0.f; rq[h][(1 - tc) * 16 + c] = 0.f;
    }
    __syncthreads();
    if (tid < DD) {
        float a = (rs[0][tid] + rs[1][tid]) + (rs[2][tid] + rs[3][tid]);
        float b2 = (rq[0][tid] + rq[1][tid]) + (rq[2][tid] + rq[3][tid]);
        atomicAdd(&stats[tid], a);
        atomicAdd(&stats[DD + tid], b2);
    }
}

// ---------------------------------------------------------------------------
// FF (MFMA): x1 = BN1(t); mid = relu(x1@W1+b1); t2 = x1 + mid@W2+b2; stats2.
// ---------------------------------------------------------------------------
__global__ __launch_bounds__(256) void k_ff(const float* __restrict__ t, const float* __restrict__ stats,
                                            const float* __restrict__ g1, const float* __restrict__ be1,
                                            const float* __restrict__ W1, const float* __restrict__ fb1,
                                            const float* __restrict__ W2, const float* __restrict__ fb2,
                                            float* __restrict__ t2, float* __restrict__ t2n,
                                            float* __restrict__ stats2) {
    __shared__ short x1b[64 * 36];
    __shared__ float x1f[64 * 33];
    __shared__ short hm[64 * 68];
    __shared__ short sW1T[FFD * 36];
    __shared__ short sW2T[DD * 68];
    __shared__ float sc[DD], sm[DD], sbe[DD], sb2v[DD];
    __shared__ float sb1v[FFD];
    __shared__ float rs[4][DD], rq[4][DD];
    int tid = threadIdx.x;
    for (int i = tid; i < 2048; i += 256) {
        int k = i >> 6, col = i & 63;
        sW1T[col * 36 + k] = f2bf(W1[i]);
        int k2 = i >> 5, col2 = i & 31;
        sW2T[col2 * 68 + k2] = f2bf(W2[i]);
    }
    if (tid < DD) {
        float mean = stats[tid] * (1.f / 32768.f);
        float var  = stats[DD + tid] * (1.f / 32768.f) - mean * mean;
        sc[tid] = rsqrtf(var + 1e-5f) * g1[tid];
        sm[tid] = mean; sbe[tid] = be1[tid]; sb2v[tid] = fb2[tid];
    }
    if (tid < FFD) sb1v[tid] = fb1[tid];
    __syncthreads();
    size_t node0 = (size_t)blockIdx.x * 64;
    {
        int row = tid >> 2, cb = (tid & 3) * 8;
        const float* tp = &t[(node0 + row) * DD + cb];
        float4 a = *(const float4*)tp;
        float4 bq = *(const float4*)(tp + 4);
        float v0 = (a.x - sm[cb + 0]) * sc[cb + 0] + sbe[cb + 0];
        float v1 = (a.y - sm[cb + 1]) * sc[cb + 1] + sbe[cb + 1];
        float v2 = (a.z - sm[cb + 2]) * sc[cb + 2] + sbe[cb + 2];
        float v3 = (a.w - sm[cb + 3]) * sc[cb + 3] + sbe[cb + 3];
        float v4 = (bq.x - sm[cb + 4]) * sc[cb + 4] + sbe[cb + 4];
        float v5 = (bq.y - sm[cb + 5]) * sc[cb + 5] + sbe[cb + 5];
        float v6 = (bq.z - sm[cb + 6]) * sc[cb + 6] + sbe[cb + 6];
        float v7 = (bq.w - sm[cb + 7]) * sc[cb + 7] + sbe[cb + 7];
        float* xf = &x1f[row * 33 + cb];
        xf[0] = v0; xf[1] = v1; xf[2] = v2; xf[3] = v3;
        xf[4] = v4; xf[5] = v5; xf[6] = v6; xf[7] = v7;
        bf16x4 p0; p0.x = f2bf(v0); p0.y = f2bf(v1); p0.z = f2bf(v2); p0.w = f2bf(v3);
        bf16x4 p1; p1.x = f2bf(v4); p1.y = f2bf(v5); p1.z = f2bf(v6); p1.w = f2bf(v7);
        *(bf16x4*)&x1b[row * 36 + cb] = p0;
        *(bf16x4*)&x1b[row * 36 + cb + 4] = p1;
    }
    __syncthreads();
    int w = tid >> 6, lane = tid & 63, c = lane & 15, g = lane >> 4;
    f32x4 m0 = {0.f, 0.f, 0.f, 0.f}, m1 = m0, m2 = m0, m3 = m0;
    #pragma unroll
    for (int ks = 0; ks < 2; ++ks) {
        bf16x4 af = *(const bf16x4*)&x1b[(w * 16 + c) * 36 + ks * 16 + g * 4];
        mfma16(m0, af, *(const bf16x4*)&sW1T[(c) * 36 + ks * 16 + g * 4]);
        mfma16(m1, af, *(const bf16x4*)&sW1T[(16 + c) * 36 + ks * 16 + g * 4]);
        mfma16(m2, af, *(const bf16x4*)&sW1T[(32 + c) * 36 + ks * 16 + g * 4]);
        mfma16(m3, af, *(const bf16x4*)&sW1T[(48 + c) * 36 + ks * 16 + g * 4]);
    }
    {
        float b0 = sb1v[c], b1 = sb1v[16 + c], b2 = sb1v[32 + c], b3 = sb1v[48 + c];
        #pragma unroll
        for (int r = 0; r < 4; ++r) {
            short* hr = &hm[(w * 16 + g * 4 + r) * 68];
            hr[c]      = f2bf(fmaxf(m0[r] + b0, 0.f));
            hr[16 + c] = f2bf(fmaxf(m1[r] + b1, 0.f));
            hr[32 + c] = f2bf(fmaxf(m2[r] + b2, 0.f));
            hr[48 + c] = f2bf(fmaxf(m3[r] + b3, 0.f));
        }
    }
    __syncthreads();
    f32x4 f0 = {0.f, 0.f, 0.f, 0.f}, f1 = f0;
    #pragma unroll
    for (int ks = 0; ks < 4; ++ks) {
        bf16x4 af = *(const bf16x4*)&hm[(w * 16 + c) * 68 + ks * 16 + g * 4];
        mfma16(f0, af, *(const bf16x4*)&sW2T[(c) * 68 + ks * 16 + g * 4]);
        mfma16(f1, af, *(const bf16x4*)&sW2T[(16 + c) * 68 + ks * 16 + g * 4]);
    }
    __syncthreads();
    float* t2s = (float*)hm;
    float ls0 = 0.f, lq0 = 0.f, ls1 = 0.f, lq1 = 0.f;
    float bb0 = sb2v[c], bb1 = sb2v[16 + c];
    #pragma unroll
    for (int r = 0; r < 4; ++r) {
        int row = w * 16 + g * 4 + r;
        float tv0 = x1f[row * 33 + c] + f0[r] + bb0;
        t2[(node0 + row) * DD + c] = tv0;
        t2s[row * DD + c] = tv0;
        ls0 += tv0; lq0 += tv0 * tv0;
        float tv1 = x1f[row * 33 + 16 + c] + f1[r] + bb1;
        t2[(node0 + row) * DD + 16 + c] = tv1;
        t2s[row * DD + 16 + c] = tv1;
        ls1 += tv1; lq1 += tv1 * tv1;
    }
    ls0 += __shfl_xor(ls0, 16, 64); ls0 += __shfl_xor(ls0, 32, 64);
    lq0 += __shfl_xor(lq0, 16, 64); lq0 += __shfl_xor(lq0, 32, 64);
    ls1 += __shfl_xor(ls1, 16, 64); ls1 += __shfl_xor(ls1, 32, 64);
    lq1 += __shfl_xor(lq1, 16, 64); lq1 += __shfl_xor(lq1, 32, 64);
    if (g == 0) {
        rs[w][c] = ls0; rs[w][16 + c] = ls1;
        rq[w][c] = lq0; rq[w][16 + c] = lq1;
    }
    __syncthreads();
    if (tid < DD) {
        float a = (rs[0][tid] + rs[1][tid]) + (rs[2][tid] + rs[3][tid]);
        float bsum = (rq[0][tid] + rq[1][tid]) + (rq[2][tid] + rq[3][tid]);
        atomicAdd(&stats2[tid], a);
        atomicAdd(&stats2[DD + tid], bsum);
    }
    if (t2n) {
        int bb = (int)(node0 >> 9), nn0 = (int)(node0 & 511);
        for (int i = tid; i < 512; i += 256) {
            int row = i >> 3, c4 = i & 7;
            float4 v = *(const float4*)&t2s[row * DD + c4 * 4];
            *(float4*)&t2n[(size_t)(nn0 + row) * 2048 + bb * DD + c4 * 4] = v;
        }
    }
}

// ---------------------------------------------------------------------------
// Final: out = BN2(t2) @ out_W + out_b  (MFMA).  Block = 64 nodes.
// ---------------------------------------------------------------------------
__global__ __launch_bounds__(256) void k_out(const float* __restrict__ t2, const float* __restrict__ stats,
                                             const float* __restrict__ g2, const float* __restrict__ be2,
                                             const float* __restrict__ outW, const float* __restrict__ outb,
                                             float* __restrict__ out) {
    __shared__ short x1b[64 * 36];
    __shared__ short sWoT[DD * 36];
    __shared__ float scv[DD], offv[DD], sbo[DD];
    int tid = threadIdx.x;
    for (int i = tid; i < 1024; i += 256) {
        int k = i >> 5, col = i & 31;
        sWoT[col * 36 + k] = f2bf(outW[i]);
    }
    if (tid < DD) {
        float mean = stats[tid] * (1.f / 32768.f);
        float var  = stats[DD + tid] * (1.f / 32768.f) - mean * mean;
        float sc = rsqrtf(var + 1e-5f) * g2[tid];
        scv[tid] = sc; offv[tid] = be2[tid] - mean * sc;
        sbo[tid] = outb[tid];
    }
    __syncthreads();
    size_t node0 = (size_t)blockIdx.x * 64;
    {
        int row = tid >> 2, cb = (tid & 3) * 8;
        const float* tp = &t2[(node0 + row) * DD + cb];
        float4 a = *(const float4*)tp;
        float4 bq = *(const float4*)(tp + 4);
        bf16x4 p0, p1;
        p0.x = f2bf(fmaf(a.x, scv[cb + 0], offv[cb + 0]));
        p0.y = f2bf(fmaf(a.y, scv[cb + 1], offv[cb + 1]));
        p0.z = f2bf(fmaf(a.z, scv[cb + 2], offv[cb + 2]));
        p0.w = f2bf(fmaf(a.w, scv[cb + 3], offv[cb + 3]));
        p1.x = f2bf(fmaf(bq.x, scv[cb + 4], offv[cb + 4]));
        p1.y = f2bf(fmaf(bq.y, scv[cb + 5], offv[cb + 5]));
        p1.z = f2bf(fmaf(bq.z, scv[cb + 6], offv[cb + 6]));
        p1.w = f2bf(fmaf(bq.w, scv[cb + 7], offv[cb + 7]));
        *(bf16x4*)&x1b[row * 36 + cb] = p0;
        *(bf16x4*)&x1b[row * 36 + cb + 4] = p1;
    }
    __syncthreads();
    int w = tid >> 6, lane = tid & 63, c = lane & 15, g = lane >> 4;
    f32x4 a0 = {0.f, 0.f, 0.f, 0.f}, a1 = a0;
    #pragma unroll
    for (int ks = 0; ks < 2; ++ks) {
        bf16x4 af = *(const bf16x4*)&x1b[(w * 16 + c) * 36 + ks * 16 + g * 4];
        mfma16(a0, af, *(const bf16x4*)&sWoT[(c) * 36 + ks * 16 + g * 4]);
        mfma16(a1, af, *(const bf16x4*)&sWoT[(16 + c) * 36 + ks * 16 + g * 4]);
    }
    float b0 = sbo[c], b1 = sbo[16 + c];
    #pragma unroll
    for (int r = 0; r < 4; ++r) {
        int row = w * 16 + g * 4 + r;
        out[(node0 + row) * DD + c]      = a0[r] + b0;
        out[(node0 + row) * DD + 16 + c] = a1[r] + b1;
    }
}

// ---------------------------------------------------------------------------
extern "C" void kernel_launch(void* const* d_in, const int* in_sizes, int n_in,
                              void* d_out, int out_size, void* d_ws, size_t ws_size,
                              hipStream_t stream) {
    const float* H    = (const float*)d_in[0];
    const int*   ei   = (const int*)  d_in[1];
    const float* eW1  = (const float*)d_in[2];
    const float* eb1  = (const float*)d_in[3];
    const float* eW2  = (const float*)d_in[4];
    const float* eb2  = (const float*)d_in[5];
    const float* elg  = (const float*)d_in[6];
    const float* elb  = (const float*)d_in[7];
    const float* gW   = (const float*)d_in[8];
    const float* gb   = (const float*)d_in[9];
    const float* Wq   = (const float*)d_in[10];
    const float* Wk   = (const float*)d_in[11];
    const float* Wv   = (const float*)d_in[12];
    const float* Wo   = (const float*)d_in[13];
    const float* bn1g = (const float*)d_in[14];
    const float* bn1b = (const float*)d_in[15];
    const float* fW1  = (const float*)d_in[16];
    const float* fb1  = (const float*)d_in[17];
    const float* fW2  = (const float*)d_in[18];
    const float* fb2  = (const float*)d_in[19];
    const float* bn2g = (const float*)d_in[20];
    const float* bn2b = (const float*)d_in[21];
    const float* oW   = (const float*)d_in[22];
    const float* obv  = (const float*)d_in[23];
    float* out = (float*)d_out;

    float* ws = (float*)d_ws;
    const size_t BIGSZ = (size_t)BB * NN * DD;   // 1048576 floats
    float* xb  = ws;                  // emb batch-major
    float* xt  = ws + 1 * BIGSZ;      // emb node-major
    float* hA  = ws + 2 * BIGSZ;      // hop1 out (node-major)
    float* hB  = ws + 3 * BIGSZ;      // t2 batch-major
    short* qb2 = (short*)(ws + 4 * BIGSZ);
    short* kb2 = qb2 + BIGSZ;
    short* vb2 = (short*)(ws + 5 * BIGSZ);
    float* t2n = ws + 6 * BIGSZ;      // t2 node-major
    float* tb  = ws + 7 * BIGSZ;      // t batch-major
    float* smalls = ws + 8 * BIGSZ;
    float* cnt_f   = smalls;
    int*   csr_off = (int*)(smalls + 512);
    int*   csr_src = (int*)(smalls + 512 + 516);
    float* stats   = smalls + 512 + 516 + 8192;   // 256: [l][bn1|bn2][64]

    k_embcsr<<<513, 256, 0, stream>>>(H, eW1, eb1, eW2, eb2, elg, elb, xb, xt,
                                      ei, cnt_f, csr_off, csr_src, stats);

    for (int l = 0; l < 2; ++l) {
        const float* gW0 = gW + (size_t)(l * 2 + 0) * 128 * DD;
        const float* gW1 = gW + (size_t)(l * 2 + 1) * 128 * DD;
        const float* gb0 = gb + (size_t)(l * 2 + 0) * DD;
        const float* gb1 = gb + (size_t)(l * 2 + 1) * DD;
        float* st1 = stats + l * 128;
        float* st2 = stats + l * 128 + 64;
        const float* pstats = (l == 0) ? nullptr : stats + 64;
        const float* pg = (l == 0) ? nullptr : bn2g;
        const float* pb = (l == 0) ? nullptr : bn2b;
        const float* gsrc = (l == 0) ? xt : t2n;
        const float* xres = (l == 0) ? xb : hB;

        k_gnn1<<<NN * 2, 256, 0, stream>>>(gsrc, hA, cnt_f, csr_off, csr_src, gW0, gb0,
                                           pstats, pg, pb);
        k_gnn2<<<NN * 2, 256, 0, stream>>>(hA, cnt_f, csr_off, csr_src, gW1, gb1,
                                           gsrc, pstats, pg, pb,
                                           Wq + l * DD * DD, Wk + l * DD * DD, Wv + l * DD * DD,
                                           qb2, kb2, vb2);
        k_attn_proj<<<BB * 16, 256, 0, stream>>>(qb2, kb2, vb2, xres, pstats, pg, pb,
                                                 Wo + l * DD * DD, tb, st1);
        k_ff<<<512, 256, 0, stream>>>(tb, st1, bn1g + l * DD, bn1b + l * DD,
                                      fW1 + l * DD * FFD, fb1 + l * FFD,
                                      fW2 + l * FFD * DD, fb2 + l * DD,
                                      hB, (l == 0) ? t2n : nullptr, st2);
    }
    k_out<<<512, 256, 0, stream>>>(hB, stats + 192, bn2g + DD, bn2b + DD, oW, obv, out);
}

// Round 14
// 184.857 us; speedup vs baseline: 1.1611x; 1.1611x over previous
//
#include <hip/hip_runtime.h>
#include <hip/hip_bf16.h>

#define BB 64
#define NN 512
#define DIN 33
#define DD 32
#define EE 8192
#define NHEADS 4
#define DH 8
#define FFD 64

typedef __attribute__((ext_vector_type(4))) float f32x4;
typedef __attribute__((ext_vector_type(4))) short bf16x4;

static __device__ __forceinline__ short f2bf(float x) {
    unsigned u = __float_as_uint(x);
    u = (u + 0x7FFFu + ((u >> 16) & 1u)) >> 16;
    return (short)u;
}

static __device__ __forceinline__ unsigned pack_trunc(float a, float b) {
    return (__float_as_uint(a) >> 16) | (__float_as_uint(b) & 0xFFFF0000u);
}

static __device__ __forceinline__ void mfma16(f32x4& d, bf16x4 a, bf16x4 b) {
#if __has_builtin(__builtin_amdgcn_mfma_f32_16x16x16bf16_1k)
    d = __builtin_amdgcn_mfma_f32_16x16x16bf16_1k(a, b, d, 0, 0, 0);
#else
    asm volatile("s_nop 1\n\tv_mfma_f32_16x16x16_bf16 %0, %1, %2, %0\n\ts_nop 7"
                 : "+v"(d) : "v"(a), "v"(b));
#endif
}

// ---------------------------------------------------------------------------
// Embedding (blocks 0..511, 64 nodes each, shuffle-based) + CSR (block 512,
// 8-deep batched edge processing for latency hiding).
// ---------------------------------------------------------------------------
__global__ __launch_bounds__(256) void k_embcsr(const float* __restrict__ H,
                                                const float* __restrict__ W1, const float* __restrict__ b1,
                                                const float* __restrict__ W2, const float* __restrict__ b2,
                                                const float* __restrict__ g,  const float* __restrict__ be,
                                                float* __restrict__ xb, float* __restrict__ xt,
                                                const int* __restrict__ ei,
                                                float* __restrict__ cnt_f,
                                                int* __restrict__ csr_off,
                                                int* __restrict__ csr_src,
                                                float* __restrict__ stats) {
    __shared__ float sW1[DIN * DD];
    __shared__ float sW2[DD * DD];
    __shared__ float sb1[DD], sb2[DD], sg[DD], sbe[DD];
    __shared__ int cnt_s[NN];
    __shared__ int wsum[4];
    int tid = threadIdx.x;
    if (blockIdx.x == 512) {
        // ---- CSR path (batched 8-deep) ----
        cnt_s[tid] = 0; cnt_s[tid + 256] = 0;
        stats[tid] = 0.f;   // [2 layers][bn1|bn2][sum|sumsq][32]
        __syncthreads();
        const int* src = ei;
        const int* dst = ei + EE;
        #pragma unroll
        for (int r = 0; r < 4; ++r) {
            int base = r * 2048 + tid * 8;
            int4 d0 = *(const int4*)&dst[base];
            int4 d1 = *(const int4*)&dst[base + 4];
            atomicAdd(&cnt_s[d0.x], 1); atomicAdd(&cnt_s[d0.y], 1);
            atomicAdd(&cnt_s[d0.z], 1); atomicAdd(&cnt_s[d0.w], 1);
            atomicAdd(&cnt_s[d1.x], 1); atomicAdd(&cnt_s[d1.y], 1);
            atomicAdd(&cnt_s[d1.z], 1); atomicAdd(&cnt_s[d1.w], 1);
        }
        __syncthreads();
        int c0 = cnt_s[2 * tid], c1 = cnt_s[2 * tid + 1];
        int cp = c0 + c1;
        int lane = tid & 63, w = tid >> 6;
        int sc = cp;
        #pragma unroll
        for (int off = 1; off < 64; off <<= 1) {
            int v = __shfl_up(sc, off, 64);
            if (lane >= off) sc += v;
        }
        if (lane == 63) wsum[w] = sc;
        __syncthreads();
        if (tid == 0) {
            int a = 0;
            #pragma unroll
            for (int i = 0; i < 4; ++i) { int t = wsum[i]; wsum[i] = a; a += t; }
        }
        __syncthreads();
        int excl = sc - cp + wsum[w];
        cnt_f[2 * tid] = (float)c0; cnt_f[2 * tid + 1] = (float)c1;
        csr_off[2 * tid] = excl; csr_off[2 * tid + 1] = excl + c0;
        if (tid == 255) csr_off[NN] = excl + cp;
        __syncthreads();
        cnt_s[2 * tid] = excl; cnt_s[2 * tid + 1] = excl + c0;
        __syncthreads();
        #pragma unroll
        for (int r = 0; r < 4; ++r) {
            int base = r * 2048 + tid * 8;
            int4 d0 = *(const int4*)&dst[base];
            int4 d1 = *(const int4*)&dst[base + 4];
            int4 s0 = *(const int4*)&src[base];
            int4 s1 = *(const int4*)&src[base + 4];
            int p;
            p = atomicAdd(&cnt_s[d0.x], 1); csr_src[p] = s0.x;
            p = atomicAdd(&cnt_s[d0.y], 1); csr_src[p] = s0.y;
            p = atomicAdd(&cnt_s[d0.z], 1); csr_src[p] = s0.z;
            p = atomicAdd(&cnt_s[d0.w], 1); csr_src[p] = s0.w;
            p = atomicAdd(&cnt_s[d1.x], 1); csr_src[p] = s1.x;
            p = atomicAdd(&cnt_s[d1.y], 1); csr_src[p] = s1.y;
            p = atomicAdd(&cnt_s[d1.z], 1); csr_src[p] = s1.z;
            p = atomicAdd(&cnt_s[d1.w], 1); csr_src[p] = s1.w;
        }
        return;
    }
    // ---- Embedding path: 64 nodes per block, 8 per pass, shuffle broadcast ----
    for (int i = tid; i < DIN * DD; i += 256) sW1[i] = W1[i];
    for (int i = tid; i < DD * DD; i += 256) sW2[i] = W2[i];
    if (tid < DD) { sb1[tid] = b1[tid]; sb2[tid] = b2[tid]; sg[tid] = g[tid]; sbe[tid] = be[tid]; }
    __syncthreads();
    int grp = tid >> 5, lane = tid & 31;
    for (int it = 0; it < 8; ++it) {
        size_t node = (size_t)blockIdx.x * 64 + it * 8 + grp;
        const float* hrow = H + node * DIN;
        float hval = hrow[lane];
        float h32  = hrow[32];
        float acc = sb1[lane];
        #pragma unroll
        for (int i = 0; i < 32; ++i) acc += __shfl(hval, i, 32) * sW1[i * DD + lane];
        acc += h32 * sW1[32 * DD + lane];
        acc = fmaxf(acc, 0.f);
        float acc2 = sb2[lane];
        #pragma unroll
        for (int i = 0; i < DD; ++i) acc2 += __shfl(acc, i, 32) * sW2[i * DD + lane];
        acc2 = fmaxf(acc2, 0.f);
        float s = acc2;
        for (int off = 16; off; off >>= 1) s += __shfl_xor(s, off, 32);
        float m = s * (1.f / 32.f);
        float dv = acc2 - m;
        float sq = dv * dv;
        for (int off = 16; off; off >>= 1) sq += __shfl_xor(sq, off, 32);
        float var = sq * (1.f / 32.f);
        float v = dv * rsqrtf(var + 1e-5f) * sg[lane] + sbe[lane];
        xb[node * DD + lane] = v;
        int b = (int)(node >> 9), n = (int)(node & 511);
        xt[(size_t)n * 2048 + b * DD + lane] = v;
    }
}

// ---------------------------------------------------------------------------
// GNN hop 1: RAW gather + post-hoc BN affine (valid since gamma>0) + MFMA.
// Block index XCD-grouped: same batch-half maps to same XCD slots.
// ---------------------------------------------------------------------------
__global__ __launch_bounds__(256) void k_gnn1(const float* __restrict__ src, float* __restrict__ ht,
                                              const float* __restrict__ cnt_f,
                                              const int* __restrict__ csr_off,
                                              const int* __restrict__ csr_src,
                                              const float* __restrict__ W, const float* __restrict__ bias,
                                              const float* __restrict__ bnstats,
                                              const float* __restrict__ bng, const float* __restrict__ bnb) {
    __shared__ short conc[32 * 132];
    __shared__ short sWt[32 * 132];
    __shared__ float sb[DD];
    __shared__ float scv[DD], offv[DD];
    int tid = threadIdx.x;
    int bi = blockIdx.x;
    int n = ((bi >> 3) << 2) | (bi & 3);   // bijective XCD grouping
    int half = (bi >> 2) & 1;
    for (int i = tid; i < 128 * DD; i += 256) {
        int k = i >> 5, d = i & 31;
        sWt[d * 132 + k] = f2bf(W[i]);
    }
    if (tid < DD) {
        sb[tid] = bias[tid];
        if (bnstats) {
            float mean = bnstats[tid] * (1.f / 32768.f);
            float var  = bnstats[DD + tid] * (1.f / 32768.f) - mean * mean;
            float sc = rsqrtf(var + 1e-5f) * bng[tid];
            scv[tid] = sc; offv[tid] = bnb[tid] - mean * sc;
        } else { scv[tid] = 1.f; offv[tid] = 0.f; }
    }
    __syncthreads();
    float4 sc4, of4;
    { int d0 = (tid * 4) & 31;
      sc4.x = scv[d0]; sc4.y = scv[d0 + 1]; sc4.z = scv[d0 + 2]; sc4.w = scv[d0 + 3];
      of4.x = offv[d0]; of4.y = offv[d0 + 1]; of4.z = offv[d0 + 2]; of4.w = offv[d0 + 3]; }
    const float* xbase = src + (size_t)half * 1024 + tid * 4;
    float4 hv = *(const float4*)&xbase[(size_t)n * 2048];
    float4 s = {0.f, 0.f, 0.f, 0.f};
    float4 mx = {-1e30f, -1e30f, -1e30f, -1e30f};
    int beg = csr_off[n], end = csr_off[n + 1];
    int idx = beg;
    for (; idx + 7 < end; idx += 8) {
        float4 v[8];
        #pragma unroll
        for (int j = 0; j < 8; ++j)
            v[j] = *(const float4*)&xbase[(size_t)csr_src[idx + j] * 2048];
        #pragma unroll
        for (int j = 0; j < 8; ++j) {
            s.x += v[j].x; s.y += v[j].y; s.z += v[j].z; s.w += v[j].w;
            mx.x = fmaxf(mx.x, v[j].x); mx.y = fmaxf(mx.y, v[j].y);
            mx.z = fmaxf(mx.z, v[j].z); mx.w = fmaxf(mx.w, v[j].w);
        }
    }
    for (; idx + 3 < end; idx += 4) {
        float4 v[4];
        #pragma unroll
        for (int j = 0; j < 4; ++j)
            v[j] = *(const float4*)&xbase[(size_t)csr_src[idx + j] * 2048];
        #pragma unroll
        for (int j = 0; j < 4; ++j) {
            s.x += v[j].x; s.y += v[j].y; s.z += v[j].z; s.w += v[j].w;
            mx.x = fmaxf(mx.x, v[j].x); mx.y = fmaxf(mx.y, v[j].y);
            mx.z = fmaxf(mx.z, v[j].z); mx.w = fmaxf(mx.w, v[j].w);
        }
    }
    for (; idx < end; ++idx) {
        float4 v0 = *(const float4*)&xbase[(size_t)csr_src[idx] * 2048];
        s.x += v0.x; s.y += v0.y; s.z += v0.z; s.w += v0.w;
        mx.x = fmaxf(mx.x, v0.x); mx.y = fmaxf(mx.y, v0.y);
        mx.z = fmaxf(mx.z, v0.z); mx.w = fmaxf(mx.w, v0.w);
    }
    float c = cnt_f[n];
    float rinv = 1.f / fmaxf(c, 1.f);
    hv.x = fmaf(hv.x, sc4.x, of4.x); hv.y = fmaf(hv.y, sc4.y, of4.y);
    hv.z = fmaf(hv.z, sc4.z, of4.z); hv.w = fmaf(hv.w, sc4.w, of4.w);
    float4 sa;
    sa.x = fmaf(s.x, sc4.x, c * of4.x); sa.y = fmaf(s.y, sc4.y, c * of4.y);
    sa.z = fmaf(s.z, sc4.z, c * of4.z); sa.w = fmaf(s.w, sc4.w, c * of4.w);
    if (c > 0.f) {
        mx.x = fmaf(mx.x, sc4.x, of4.x); mx.y = fmaf(mx.y, sc4.y, of4.y);
        mx.z = fmaf(mx.z, sc4.z, of4.z); mx.w = fmaf(mx.w, sc4.w, of4.w);
    } else { mx.x = 0.f; mx.y = 0.f; mx.z = 0.f; mx.w = 0.f; }
    int bl = tid >> 3, d0 = (tid & 7) * 4;
    short* cp = &conc[bl * 132];
    bf16x4 t;
    t.x = f2bf(hv.x); t.y = f2bf(hv.y); t.z = f2bf(hv.z); t.w = f2bf(hv.w);
    *(bf16x4*)&cp[d0] = t;
    t.x = f2bf(sa.x * rinv); t.y = f2bf(sa.y * rinv); t.z = f2bf(sa.z * rinv); t.w = f2bf(sa.w * rinv);
    *(bf16x4*)&cp[32 + d0] = t;
    t.x = f2bf(mx.x); t.y = f2bf(mx.y); t.z = f2bf(mx.z); t.w = f2bf(mx.w);
    *(bf16x4*)&cp[64 + d0] = t;
    t.x = f2bf(sa.x); t.y = f2bf(sa.y); t.z = f2bf(sa.z); t.w = f2bf(sa.w);
    *(bf16x4*)&cp[96 + d0] = t;
    __syncthreads();
    int wid = tid >> 6, lane = tid & 63;
    int cc = lane & 15, g = lane >> 4;
    int arow = (wid >> 1) * 16 + cc;
    int bcol = (wid & 1) * 16 + cc;
    f32x4 acc = {0.f, 0.f, 0.f, 0.f};
    #pragma unroll
    for (int ks = 0; ks < 8; ++ks) {
        bf16x4 af = *(const bf16x4*)&conc[arow * 132 + ks * 16 + g * 4];
        bf16x4 bfr = *(const bf16x4*)&sWt[bcol * 132 + ks * 16 + g * 4];
        mfma16(acc, af, bfr);
    }
    float bia = sb[bcol];
    int brow = (wid >> 1) * 16 + g * 4;
    float* obase = &ht[(size_t)n * 2048 + half * 1024 + bcol];
    #pragma unroll
    for (int r = 0; r < 4; ++r) {
        obase[(size_t)(brow + r) * DD] = fmaxf(acc[r] + bia, 0.f);
    }
}

// ---------------------------------------------------------------------------
// GNN hop 2 + QKV.  Wq pre-scaled by 1/sqrt(dh)*log2(e) (attn uses exp2f).
// Block index XCD-grouped like gnn1.
// ---------------------------------------------------------------------------
__global__ __launch_bounds__(256) void k_gnn2(const float* __restrict__ hsrc,
                                              const float* __restrict__ cnt_f,
                                              const int* __restrict__ csr_off,
                                              const int* __restrict__ csr_src,
                                              const float* __restrict__ W, const float* __restrict__ bias,
                                              const float* __restrict__ xsrc,
                                              const float* __restrict__ bnstats,
                                              const float* __restrict__ bng, const float* __restrict__ bnb,
                                              const float* __restrict__ Wq, const float* __restrict__ Wk,
                                              const float* __restrict__ Wv,
                                              short* __restrict__ qb2, short* __restrict__ kb2,
                                              short* __restrict__ vb2) {
    __shared__ short conc[32 * 132];
    __shared__ short sWt[32 * 132];
    __shared__ short sWqT[32 * 36], sWkT[32 * 36], sWvT[32 * 36];
    __shared__ short h_lds[32 * 36], x_lds[32 * 36];
    __shared__ float sb[DD];
    __shared__ float scv[DD], offv[DD];
    int tid = threadIdx.x;
    int bi = blockIdx.x;
    int n = ((bi >> 3) << 2) | (bi & 3);
    int half = (bi >> 2) & 1;
    for (int i = tid; i < 128 * DD; i += 256) {
        int k = i >> 5, d = i & 31;
        sWt[d * 132 + k] = f2bf(W[i]);
    }
    {
        const float qsc = 0.35355339059327373f * 1.44269504088896f;  // isq * log2(e)
        for (int i = tid; i < 1024; i += 256) {
            int k = i >> 5, col = i & 31;
            sWqT[col * 36 + k] = f2bf(Wq[i] * qsc);
            sWkT[col * 36 + k] = f2bf(Wk[i]);
            sWvT[col * 36 + k] = f2bf(Wv[i]);
        }
    }
    if (tid < DD) {
        sb[tid] = bias[tid];
        if (bnstats) {
            float mean = bnstats[tid] * (1.f / 32768.f);
            float var  = bnstats[DD + tid] * (1.f / 32768.f) - mean * mean;
            float sc = rsqrtf(var + 1e-5f) * bng[tid];
            scv[tid] = sc; offv[tid] = bnb[tid] - mean * sc;
        } else { scv[tid] = 1.f; offv[tid] = 0.f; }
    }
    __syncthreads();
    {
        int bl = tid >> 3, d0 = (tid & 7) * 4;
        float4 x4 = *(const float4*)&xsrc[(size_t)n * 2048 + half * 1024 + bl * 32 + d0];
        x4.x = fmaf(x4.x, scv[d0], offv[d0]);
        x4.y = fmaf(x4.y, scv[d0 + 1], offv[d0 + 1]);
        x4.z = fmaf(x4.z, scv[d0 + 2], offv[d0 + 2]);
        x4.w = fmaf(x4.w, scv[d0 + 3], offv[d0 + 3]);
        bf16x4 xp; xp.x = f2bf(x4.x); xp.y = f2bf(x4.y); xp.z = f2bf(x4.z); xp.w = f2bf(x4.w);
        *(bf16x4*)&x_lds[bl * 36 + d0] = xp;
    }
    const float* xbase = hsrc + (size_t)half * 1024 + tid * 4;
    float4 hv = *(const float4*)&xbase[(size_t)n * 2048];
    float4 s = {0.f, 0.f, 0.f, 0.f};
    float4 mx = {-1e30f, -1e30f, -1e30f, -1e30f};
    int beg = csr_off[n], end = csr_off[n + 1];
    int idx = beg;
    for (; idx + 7 < end; idx += 8) {
        float4 v[8];
        #pragma unroll
        for (int j = 0; j < 8; ++j)
            v[j] = *(const float4*)&xbase[(size_t)csr_src[idx + j] * 2048];
        #pragma unroll
        for (int j = 0; j < 8; ++j) {
            s.x += v[j].x; s.y += v[j].y; s.z += v[j].z; s.w += v[j].w;
            mx.x = fmaxf(mx.x, v[j].x); mx.y = fmaxf(mx.y, v[j].y);
            mx.z = fmaxf(mx.z, v[j].z); mx.w = fmaxf(mx.w, v[j].w);
        }
    }
    for (; idx + 3 < end; idx += 4) {
        float4 v[4];
        #pragma unroll
        for (int j = 0; j < 4; ++j)
            v[j] = *(const float4*)&xbase[(size_t)csr_src[idx + j] * 2048];
        #pragma unroll
        for (int j = 0; j < 4; ++j) {
            s.x += v[j].x; s.y += v[j].y; s.z += v[j].z; s.w += v[j].w;
            mx.x = fmaxf(mx.x, v[j].x); mx.y = fmaxf(mx.y, v[j].y);
            mx.z = fmaxf(mx.z, v[j].z); mx.w = fmaxf(mx.w, v[j].w);
        }
    }
    for (; idx < end; ++idx) {
        float4 v0 = *(const float4*)&xbase[(size_t)csr_src[idx] * 2048];
        s.x += v0.x; s.y += v0.y; s.z += v0.z; s.w += v0.w;
        mx.x = fmaxf(mx.x, v0.x); mx.y = fmaxf(mx.y, v0.y);
        mx.z = fmaxf(mx.z, v0.z); mx.w = fmaxf(mx.w, v0.w);
    }
    float c = cnt_f[n];
    float rinv = 1.f / fmaxf(c, 1.f);
    if (!(c > 0.f)) { mx.x = 0.f; mx.y = 0.f; mx.z = 0.f; mx.w = 0.f; }
    int bl = tid >> 3, d0 = (tid & 7) * 4;
    short* cp = &conc[bl * 132];
    bf16x4 t;
    t.x = f2bf(hv.x); t.y = f2bf(hv.y); t.z = f2bf(hv.z); t.w = f2bf(hv.w);
    *(bf16x4*)&cp[d0] = t;
    t.x = f2bf(s.x * rinv); t.y = f2bf(s.y * rinv); t.z = f2bf(s.z * rinv); t.w = f2bf(s.w * rinv);
    *(bf16x4*)&cp[32 + d0] = t;
    t.x = f2bf(mx.x); t.y = f2bf(mx.y); t.z = f2bf(mx.z); t.w = f2bf(mx.w);
    *(bf16x4*)&cp[64 + d0] = t;
    t.x = f2bf(s.x); t.y = f2bf(s.y); t.z = f2bf(s.z); t.w = f2bf(s.w);
    *(bf16x4*)&cp[96 + d0] = t;
    __syncthreads();
    int wid = tid >> 6, lane = tid & 63;
    int cc = lane & 15, g = lane >> 4;
    int arow = (wid >> 1) * 16 + cc;
    int bcol = (wid & 1) * 16 + cc;
    f32x4 acc = {0.f, 0.f, 0.f, 0.f};
    #pragma unroll
    for (int ks = 0; ks < 8; ++ks) {
        bf16x4 af = *(const bf16x4*)&conc[arow * 132 + ks * 16 + g * 4];
        bf16x4 bfr = *(const bf16x4*)&sWt[bcol * 132 + ks * 16 + g * 4];
        mfma16(acc, af, bfr);
    }
    float bia = sb[bcol];
    int brow = (wid >> 1) * 16 + g * 4;
    #pragma unroll
    for (int r = 0; r < 4; ++r) {
        h_lds[(brow + r) * 36 + bcol] = f2bf(fmaxf(acc[r] + bia, 0.f));
    }
    __syncthreads();
    int tr = wid >> 1, tc = wid & 1;
    f32x4 qa = {0.f, 0.f, 0.f, 0.f}, ka = qa, va = qa;
    #pragma unroll
    for (int ks = 0; ks < 2; ++ks) {
        bf16x4 ha = *(const bf16x4*)&h_lds[(tr * 16 + cc) * 36 + ks * 16 + g * 4];
        bf16x4 xa = *(const bf16x4*)&x_lds[(tr * 16 + cc) * 36 + ks * 16 + g * 4];
        bf16x4 wq = *(const bf16x4*)&sWqT[(tc * 16 + cc) * 36 + ks * 16 + g * 4];
        bf16x4 wk = *(const bf16x4*)&sWkT[(tc * 16 + cc) * 36 + ks * 16 + g * 4];
        bf16x4 wv = *(const bf16x4*)&sWvT[(tc * 16 + cc) * 36 + ks * 16 + g * 4];
        mfma16(qa, ha, wq);
        mfma16(ka, ha, wk);
        mfma16(va, xa, wv);
    }
    int dcol = tc * 16 + cc;
    size_t base = ((size_t)(half * 32 + tr * 16 + g * 4) * NN + n) * DD + dcol;
    #pragma unroll
    for (int r = 0; r < 4; ++r) {
        size_t p = base + (size_t)r * (NN * DD);
        qb2[p] = f2bf(qa[r]);
        kb2[p] = f2bf(ka[r]);
        vb2[p] = f2bf(va[r]);
    }
}

// ---------------------------------------------------------------------------
// Attention (exp2 softmax, no max) + Wo proj + residual + BN1 stats.
// Grid 512: block = (b XCD-grouped, 64-q-row slice qs of 8), wave = head,
// 4 q-tiles/wave.  K from global (prefetched), V in LDS.
// ---------------------------------------------------------------------------
__global__ __launch_bounds__(256) void k_attn_proj(const short* __restrict__ qb2,
                                                   const short* __restrict__ kb2,
                                                   const short* __restrict__ vb2,
                                                   const float* __restrict__ x,
                                                   const float* __restrict__ bnstats,
                                                   const float* __restrict__ bng,
                                                   const float* __restrict__ bnb,
                                                   const float* __restrict__ Wo,
                                                   float* __restrict__ t,
                                                   float* __restrict__ stats) {
    __shared__ short Vt[NHEADS * DH * 528];   // [h][d][528] bf16, 33 KB
    __shared__ short Ot[64 * 36];
    __shared__ short sWoT[DD * 36];
    __shared__ float rs[4][DD], rq[4][DD];
    __shared__ float scv[DD], offv[DD];
    int i = blockIdx.x;
    int b = ((i & 7) << 3) | ((i >> 3) & 7);   // XCD-grouped b
    int qs = i >> 6;
    int tid = threadIdx.x;

    for (int j = tid; j < 1024; j += 256) {
        int k = j >> 5, col = j & 31;
        sWoT[col * 36 + k] = f2bf(Wo[j]);
    }
    if (tid < DD) {
        if (bnstats) {
            float mean = bnstats[tid] * (1.f / 32768.f);
            float var  = bnstats[DD + tid] * (1.f / 32768.f) - mean * mean;
            float sc = rsqrtf(var + 1e-5f) * bng[tid];
            scv[tid] = sc; offv[tid] = bnb[tid] - mean * sc;
        } else { scv[tid] = 1.f; offv[tid] = 0.f; }
    }
    {
        size_t g0 = ((size_t)b * NN + tid * 2) * DD;
        #pragma unroll
        for (int h2 = 0; h2 < 4; ++h2) {
            uint4 v0 = *(const uint4*)&vb2[g0 + h2 * 8];
            uint4 v1 = *(const uint4*)&vb2[g0 + DD + h2 * 8];
            unsigned* vt = (unsigned*)&Vt[h2 * DH * 528];
            vt[0 * 264 + tid] = (v0.x & 0xFFFFu) | (v1.x << 16);
            vt[1 * 264 + tid] = (v0.x >> 16)     | (v1.x & 0xFFFF0000u);
            vt[2 * 264 + tid] = (v0.y & 0xFFFFu) | (v1.y << 16);
            vt[3 * 264 + tid] = (v0.y >> 16)     | (v1.y & 0xFFFF0000u);
            vt[4 * 264 + tid] = (v0.z & 0xFFFFu) | (v1.z << 16);
            vt[5 * 264 + tid] = (v0.z >> 16)     | (v1.z & 0xFFFF0000u);
            vt[6 * 264 + tid] = (v0.w & 0xFFFFu) | (v1.w << 16);
            vt[7 * 264 + tid] = (v0.w >> 16)     | (v1.w & 0xFFFF0000u);
        }
    }
    __syncthreads();

    int h = tid >> 6, lane = tid & 63;
    int c = lane & 15, g = lane >> 4;
    int c7 = c & 7;
    bf16x4 z4 = {0, 0, 0, 0};
    bf16x4 qf0 = z4, qf1 = z4, qf2 = z4, qf3 = z4;
    if (g < 2) {
        const short* qbase = &qb2[(((size_t)b * NN + qs * 64) * DD) + h * DH + g * 4];
        qf0 = *(const bf16x4*)&qbase[(size_t)(c) * DD];
        qf1 = *(const bf16x4*)&qbase[(size_t)(16 + c) * DD];
        qf2 = *(const bf16x4*)&qbase[(size_t)(32 + c) * DD];
        qf3 = *(const bf16x4*)&qbase[(size_t)(48 + c) * DD];
    }
    const short* kbase = &kb2[((size_t)b * NN) * DD + h * DH + g * 4];
    float l0 = 0.f, l1 = 0.f, l2 = 0.f, l3 = 0.f;
    f32x4 o0 = {0.f, 0.f, 0.f, 0.f}, o1 = o0, o2 = o0, o3 = o0;
    union U { unsigned u[2]; bf16x4 v4; };

    bf16x4 kf_cur = z4;
    if (g < 2) kf_cur = *(const bf16x4*)&kbase[(size_t)(c) * DD];
    for (int kc = 0; kc < 32; ++kc) {
        bf16x4 kf = kf_cur;
        if (g < 2 && kc < 31)
            kf_cur = *(const bf16x4*)&kbase[(size_t)((kc + 1) * 16 + c) * DD];
        bf16x4 vf = z4;
        {
            bf16x4 vl = *(const bf16x4*)&Vt[(h * DH + c7) * 528 + kc * 16 + g * 4];
            if (c < 8) vf = vl;
        }
        f32x4 st0 = {0.f, 0.f, 0.f, 0.f}, st1 = st0, st2 = st0, st3 = st0;
        mfma16(st0, kf, qf0);
        mfma16(st1, kf, qf1);
        mfma16(st2, kf, qf2);
        mfma16(st3, kf, qf3);
        {
            float p0 = exp2f(st0[0]), p1 = exp2f(st0[1]), p2 = exp2f(st0[2]), p3 = exp2f(st0[3]);
            l0 += (p0 + p1) + (p2 + p3);
            U pu; pu.u[0] = pack_trunc(p0, p1); pu.u[1] = pack_trunc(p2, p3);
            mfma16(o0, vf, pu.v4);
        }
        {
            float p0 = exp2f(st1[0]), p1 = exp2f(st1[1]), p2 = exp2f(st1[2]), p3 = exp2f(st1[3]);
            l1 += (p0 + p1) + (p2 + p3);
            U pu; pu.u[0] = pack_trunc(p0, p1); pu.u[1] = pack_trunc(p2, p3);
            mfma16(o1, vf, pu.v4);
        }
        {
            float p0 = exp2f(st2[0]), p1 = exp2f(st2[1]), p2 = exp2f(st2[2]), p3 = exp2f(st2[3]);
            l2 += (p0 + p1) + (p2 + p3);
            U pu; pu.u[0] = pack_trunc(p0, p1); pu.u[1] = pack_trunc(p2, p3);
            mfma16(o2, vf, pu.v4);
        }
        {
            float p0 = exp2f(st3[0]), p1 = exp2f(st3[1]), p2 = exp2f(st3[2]), p3 = exp2f(st3[3]);
            l3 += (p0 + p1) + (p2 + p3);
            U pu; pu.u[0] = pack_trunc(p0, p1); pu.u[1] = pack_trunc(p2, p3);
            mfma16(o3, vf, pu.v4);
        }
    }
    l0 += __shfl_xor(l0, 16, 64); l0 += __shfl_xor(l0, 32, 64);
    l1 += __shfl_xor(l1, 16, 64); l1 += __shfl_xor(l1, 32, 64);
    l2 += __shfl_xor(l2, 16, 64); l2 += __shfl_xor(l2, 32, 64);
    l3 += __shfl_xor(l3, 16, 64); l3 += __shfl_xor(l3, 32, 64);
    if (g < 2) {
        float inv0 = 1.f / l0, inv1 = 1.f / l1, inv2 = 1.f / l2, inv3 = 1.f / l3;
        int fb = h * DH + g * 4;
        #pragma unroll
        for (int r = 0; r < 4; ++r) {
            Ot[(c) * 36 + fb + r]      = f2bf(o0[r] * inv0);
            Ot[(16 + c) * 36 + fb + r] = f2bf(o1[r] * inv1);
            Ot[(32 + c) * 36 + fb + r] = f2bf(o2[r] * inv2);
            Ot[(48 + c) * 36 + fb + r] = f2bf(o3[r] * inv3);
        }
    }
    __syncthreads();
    f32x4 pa0 = {0.f, 0.f, 0.f, 0.f}, pa1 = pa0;
    #pragma unroll
    for (int ks = 0; ks < 2; ++ks) {
        bf16x4 af = *(const bf16x4*)&Ot[(h * 16 + c) * 36 + ks * 16 + g * 4];
        bf16x4 b0 = *(const bf16x4*)&sWoT[c * 36 + ks * 16 + g * 4];
        bf16x4 b1 = *(const bf16x4*)&sWoT[(16 + c) * 36 + ks * 16 + g * 4];
        mfma16(pa0, af, b0);
        mfma16(pa1, af, b1);
    }
    float sc0 = scv[c], of0 = offv[c], sc1 = scv[16 + c], of1 = offv[16 + c];
    float ls0 = 0.f, lq0 = 0.f, ls1 = 0.f, lq1 = 0.f;
    size_t rowbase = ((size_t)b * NN + qs * 64 + h * 16 + g * 4) * DD;
    #pragma unroll
    for (int r = 0; r < 4; ++r) {
        float xv0 = fmaf(x[rowbase + (size_t)r * DD + c], sc0, of0);
        float tv0 = xv0 + pa0[r];
        t[rowbase + (size_t)r * DD + c] = tv0;
        ls0 += tv0; lq0 += tv0 * tv0;
        float xv1 = fmaf(x[rowbase + (size_t)r * DD + 16 + c], sc1, of1);
        float tv1 = xv1 + pa1[r];
        t[rowbase + (size_t)r * DD + 16 + c] = tv1;
        ls1 += tv1; lq1 += tv1 * tv1;
    }
    ls0 += __shfl_xor(ls0, 16, 64); ls0 += __shfl_xor(ls0, 32, 64);
    lq0 += __shfl_xor(lq0, 16, 64); lq0 += __shfl_xor(lq0, 32, 64);
    ls1 += __shfl_xor(ls1, 16, 64); ls1 += __shfl_xor(ls1, 32, 64);
    lq1 += __shfl_xor(lq1, 16, 64); lq1 += __shfl_xor(lq1, 32, 64);
    if (g == 0) {
        rs[h][c] = ls0; rs[h][16 + c] = ls1;
        rq[h][c] = lq0; rq[h][16 + c] = lq1;
    }
    __syncthreads();
    if (tid < DD) {
        float a = (rs[0][tid] + rs[1][tid]) + (rs[2][tid] + rs[3][tid]);
        float b2 = (rq[0][tid] + rq[1][tid]) + (rq[2][tid] + rq[3][tid]);
        atomicAdd(&stats[tid], a);
        atomicAdd(&stats[DD + tid], b2);
    }
}

// ---------------------------------------------------------------------------
// FF (MFMA): x1 = BN1(t); mid = relu(x1@W1+b1); t2 = x1 + mid@W2+b2; stats2.
// ---------------------------------------------------------------------------
__global__ __launch_bounds__(256) void k_ff(const float* __restrict__ t, const float* __restrict__ stats,
                                            const float* __restrict__ g1, const float* __restrict__ be1,
                                            const float* __restrict__ W1, const float* __restrict__ fb1,
                                            const float* __restrict__ W2, const float* __restrict__ fb2,
                                            float* __restrict__ t2, float* __restrict__ t2n,
                                            float* __restrict__ stats2) {
    __shared__ short x1b[64 * 36];
    __shared__ float x1f[64 * 33];
    __shared__ short hm[64 * 68];
    __shared__ short sW1T[FFD * 36];
    __shared__ short sW2T[DD * 68];
    __shared__ float sc[DD], sm[DD], sbe[DD], sb2v[DD];
    __shared__ float sb1v[FFD];
    __shared__ float rs[4][DD], rq[4][DD];
    int tid = threadIdx.x;
    for (int i = tid; i < 2048; i += 256) {
        int k = i >> 6, col = i & 63;
        sW1T[col * 36 + k] = f2bf(W1[i]);
        int k2 = i >> 5, col2 = i & 31;
        sW2T[col2 * 68 + k2] = f2bf(W2[i]);
    }
    if (tid < DD) {
        float mean = stats[tid] * (1.f / 32768.f);
        float var  = stats[DD + tid] * (1.f / 32768.f) - mean * mean;
        sc[tid] = rsqrtf(var + 1e-5f) * g1[tid];
        sm[tid] = mean; sbe[tid] = be1[tid]; sb2v[tid] = fb2[tid];
    }
    if (tid < FFD) sb1v[tid] = fb1[tid];
    __syncthreads();
    size_t node0 = (size_t)blockIdx.x * 64;
    {
        int row = tid >> 2, cb = (tid & 3) * 8;
        const float* tp = &t[(node0 + row) * DD + cb];
        float4 a = *(const float4*)tp;
        float4 bq = *(const float4*)(tp + 4);
        float v0 = (a.x - sm[cb + 0]) * sc[cb + 0] + sbe[cb + 0];
        float v1 = (a.y - sm[cb + 1]) * sc[cb + 1] + sbe[cb + 1];
        float v2 = (a.z - sm[cb + 2]) * sc[cb + 2] + sbe[cb + 2];
        float v3 = (a.w - sm[cb + 3]) * sc[cb + 3] + sbe[cb + 3];
        float v4 = (bq.x - sm[cb + 4]) * sc[cb + 4] + sbe[cb + 4];
        float v5 = (bq.y - sm[cb + 5]) * sc[cb + 5] + sbe[cb + 5];
        float v6 = (bq.z - sm[cb + 6]) * sc[cb + 6] + sbe[cb + 6];
        float v7 = (bq.w - sm[cb + 7]) * sc[cb + 7] + sbe[cb + 7];
        float* xf = &x1f[row * 33 + cb];
        xf[0] = v0; xf[1] = v1; xf[2] = v2; xf[3] = v3;
        xf[4] = v4; xf[5] = v5; xf[6] = v6; xf[7] = v7;
        bf16x4 p0; p0.x = f2bf(v0); p0.y = f2bf(v1); p0.z = f2bf(v2); p0.w = f2bf(v3);
        bf16x4 p1; p1.x = f2bf(v4); p1.y = f2bf(v5); p1.z = f2bf(v6); p1.w = f2bf(v7);
        *(bf16x4*)&x1b[row * 36 + cb] = p0;
        *(bf16x4*)&x1b[row * 36 + cb + 4] = p1;
    }
    __syncthreads();
    int w = tid >> 6, lane = tid & 63, c = lane & 15, g = lane >> 4;
    f32x4 m0 = {0.f, 0.f, 0.f, 0.f}, m1 = m0, m2 = m0, m3 = m0;
    #pragma unroll
    for (int ks = 0; ks < 2; ++ks) {
        bf16x4 af = *(const bf16x4*)&x1b[(w * 16 + c) * 36 + ks * 16 + g * 4];
        mfma16(m0, af, *(const bf16x4*)&sW1T[(c) * 36 + ks * 16 + g * 4]);
        mfma16(m1, af, *(const bf16x4*)&sW1T[(16 + c) * 36 + ks * 16 + g * 4]);
        mfma16(m2, af, *(const bf16x4*)&sW1T[(32 + c) * 36 + ks * 16 + g * 4]);
        mfma16(m3, af, *(const bf16x4*)&sW1T[(48 + c) * 36 + ks * 16 + g * 4]);
    }
    {
        float b0 = sb1v[c], b1 = sb1v[16 + c], b2 = sb1v[32 + c], b3 = sb1v[48 + c];
        #pragma unroll
        for (int r = 0; r < 4; ++r) {
            short* hr = &hm[(w * 16 + g * 4 + r) * 68];
            hr[c]      = f2bf(fmaxf(m0[r] + b0, 0.f));
            hr[16 + c] = f2bf(fmaxf(m1[r] + b1, 0.f));
            hr[32 + c] = f2bf(fmaxf(m2[r] + b2, 0.f));
            hr[48 + c] = f2bf(fmaxf(m3[r] + b3, 0.f));
        }
    }
    __syncthreads();
    f32x4 f0 = {0.f, 0.f, 0.f, 0.f}, f1 = f0;
    #pragma unroll
    for (int ks = 0; ks < 4; ++ks) {
        bf16x4 af = *(const bf16x4*)&hm[(w * 16 + c) * 68 + ks * 16 + g * 4];
        mfma16(f0, af, *(const bf16x4*)&sW2T[(c) * 68 + ks * 16 + g * 4]);
        mfma16(f1, af, *(const bf16x4*)&sW2T[(16 + c) * 68 + ks * 16 + g * 4]);
    }
    __syncthreads();
    float* t2s = (float*)hm;
    float ls0 = 0.f, lq0 = 0.f, ls1 = 0.f, lq1 = 0.f;
    float bb0 = sb2v[c], bb1 = sb2v[16 + c];
    #pragma unroll
    for (int r = 0; r < 4; ++r) {
        int row = w * 16 + g * 4 + r;
        float tv0 = x1f[row * 33 + c] + f0[r] + bb0;
        t2[(node0 + row) * DD + c] = tv0;
        t2s[row * DD + c] = tv0;
        ls0 += tv0; lq0 += tv0 * tv0;
        float tv1 = x1f[row * 33 + 16 + c] + f1[r] + bb1;
        t2[(node0 + row) * DD + 16 + c] = tv1;
        t2s[row * DD + 16 + c] = tv1;
        ls1 += tv1; lq1 += tv1 * tv1;
    }
    ls0 += __shfl_xor(ls0, 16, 64); ls0 += __shfl_xor(ls0, 32, 64);
    lq0 += __shfl_xor(lq0, 16, 64); lq0 += __shfl_xor(lq0, 32, 64);
    ls1 += __shfl_xor(ls1, 16, 64); ls1 += __shfl_xor(ls1, 32, 64);
    lq1 += __shfl_xor(lq1, 16, 64); lq1 += __shfl_xor(lq1, 32, 64);
    if (g == 0) {
        rs[w][c] = ls0; rs[w][16 + c] = ls1;
        rq[w][c] = lq0; rq[w][16 + c] = lq1;
    }
    __syncthreads();
    if (tid < DD) {
        float a = (rs[0][tid] + rs[1][tid]) + (rs[2][tid] + rs[3][tid]);
        float bsum = (rq[0][tid] + rq[1][tid]) + (rq[2][tid] + rq[3][tid]);
        atomicAdd(&stats2[tid], a);
        atomicAdd(&stats2[DD + tid], bsum);
    }
    if (t2n) {
        int bb = (int)(node0 >> 9), nn0 = (int)(node0 & 511);
        for (int i = tid; i < 512; i += 256) {
            int row = i >> 3, c4 = i & 7;
            float4 v = *(const float4*)&t2s[row * DD + c4 * 4];
            *(float4*)&t2n[(size_t)(nn0 + row) * 2048 + bb * DD + c4 * 4] = v;
        }
    }
}

// ---------------------------------------------------------------------------
// Final: out = BN2(t2) @ out_W + out_b  (MFMA).  Block = 64 nodes.
// ---------------------------------------------------------------------------
__global__ __launch_bounds__(256) void k_out(const float* __restrict__ t2, const float* __restrict__ stats,
                                             const float* __restrict__ g2, const float* __restrict__ be2,
                                             const float* __restrict__ outW, const float* __restrict__ outb,
                                             float* __restrict__ out) {
    __shared__ short x1b[64 * 36];
    __shared__ short sWoT[DD * 36];
    __shared__ float scv[DD], offv[DD], sbo[DD];
    int tid = threadIdx.x;
    for (int i = tid; i < 1024; i += 256) {
        int k = i >> 5, col = i & 31;
        sWoT[col * 36 + k] = f2bf(outW[i]);
    }
    if (tid < DD) {
        float mean = stats[tid] * (1.f / 32768.f);
        float var  = stats[DD + tid] * (1.f / 32768.f) - mean * mean;
        float sc = rsqrtf(var + 1e-5f) * g2[tid];
        scv[tid] = sc; offv[tid] = be2[tid] - mean * sc;
        sbo[tid] = outb[tid];
    }
    __syncthreads();
    size_t node0 = (size_t)blockIdx.x * 64;
    {
        int row = tid >> 2, cb = (tid & 3) * 8;
        const float* tp = &t2[(node0 + row) * DD + cb];
        float4 a = *(const float4*)tp;
        float4 bq = *(const float4*)(tp + 4);
        bf16x4 p0, p1;
        p0.x = f2bf(fmaf(a.x, scv[cb + 0], offv[cb + 0]));
        p0.y = f2bf(fmaf(a.y, scv[cb + 1], offv[cb + 1]));
        p0.z = f2bf(fmaf(a.z, scv[cb + 2], offv[cb + 2]));
        p0.w = f2bf(fmaf(a.w, scv[cb + 3], offv[cb + 3]));
        p1.x = f2bf(fmaf(bq.x, scv[cb + 4], offv[cb + 4]));
        p1.y = f2bf(fmaf(bq.y, scv[cb + 5], offv[cb + 5]));
        p1.z = f2bf(fmaf(bq.z, scv[cb + 6], offv[cb + 6]));
        p1.w = f2bf(fmaf(bq.w, scv[cb + 7], offv[cb + 7]));
        *(bf16x4*)&x1b[row * 36 + cb] = p0;
        *(bf16x4*)&x1b[row * 36 + cb + 4] = p1;
    }
    __syncthreads();
    int w = tid >> 6, lane = tid & 63, c = lane & 15, g = lane >> 4;
    f32x4 a0 = {0.f, 0.f, 0.f, 0.f}, a1 = a0;
    #pragma unroll
    for (int ks = 0; ks < 2; ++ks) {
        bf16x4 af = *(const bf16x4*)&x1b[(w * 16 + c) * 36 + ks * 16 + g * 4];
        mfma16(a0, af, *(const bf16x4*)&sWoT[(c) * 36 + ks * 16 + g * 4]);
        mfma16(a1, af, *(const bf16x4*)&sWoT[(16 + c) * 36 + ks * 16 + g * 4]);
    }
    float b0 = sbo[c], b1 = sbo[16 + c];
    #pragma unroll
    for (int r = 0; r < 4; ++r) {
        int row = w * 16 + g * 4 + r;
        out[(node0 + row) * DD + c]      = a0[r] + b0;
        out[(node0 + row) * DD + 16 + c] = a1[r] + b1;
    }
}

// ---------------------------------------------------------------------------
extern "C" void kernel_launch(void* const* d_in, const int* in_sizes, int n_in,
                              void* d_out, int out_size, void* d_ws, size_t ws_size,
                              hipStream_t stream) {
    const float* H    = (const float*)d_in[0];
    const int*   ei   = (const int*)  d_in[1];
    const float* eW1  = (const float*)d_in[2];
    const float* eb1  = (const float*)d_in[3];
    const float* eW2  = (const float*)d_in[4];
    const float* eb2  = (const float*)d_in[5];
    const float* elg  = (const float*)d_in[6];
    const float* elb  = (const float*)d_in[7];
    const float* gW   = (const float*)d_in[8];
    const float* gb   = (const float*)d_in[9];
    const float* Wq   = (const float*)d_in[10];
    const float* Wk   = (const float*)d_in[11];
    const float* Wv   = (const float*)d_in[12];
    const float* Wo   = (const float*)d_in[13];
    const float* bn1g = (const float*)d_in[14];
    const float* bn1b = (const float*)d_in[15];
    const float* fW1  = (const float*)d_in[16];
    const float* fb1  = (const float*)d_in[17];
    const float* fW2  = (const float*)d_in[18];
    const float* fb2  = (const float*)d_in[19];
    const float* bn2g = (const float*)d_in[20];
    const float* bn2b = (const float*)d_in[21];
    const float* oW   = (const float*)d_in[22];
    const float* obv  = (const float*)d_in[23];
    float* out = (float*)d_out;

    float* ws = (float*)d_ws;
    const size_t BIGSZ = (size_t)BB * NN * DD;   // 1048576 floats
    float* xb  = ws;                  // emb batch-major
    float* xt  = ws + 1 * BIGSZ;      // emb node-major
    float* hA  = ws + 2 * BIGSZ;      // hop1 out (node-major)
    float* hB  = ws + 3 * BIGSZ;      // t2 batch-major
    short* qb2 = (short*)(ws + 4 * BIGSZ);
    short* kb2 = qb2 + BIGSZ;
    short* vb2 = (short*)(ws + 5 * BIGSZ);
    float* t2n = ws + 6 * BIGSZ;      // t2 node-major
    float* tb  = ws + 7 * BIGSZ;      // t batch-major
    float* smalls = ws + 8 * BIGSZ;
    float* cnt_f   = smalls;
    int*   csr_off = (int*)(smalls + 512);
    int*   csr_src = (int*)(smalls + 512 + 516);
    float* stats   = smalls + 512 + 516 + 8192;   // 256: [l][bn1|bn2][64]

    k_embcsr<<<513, 256, 0, stream>>>(H, eW1, eb1, eW2, eb2, elg, elb, xb, xt,
                                      ei, cnt_f, csr_off, csr_src, stats);

    for (int l = 0; l < 2; ++l) {
        const float* gW0 = gW + (size_t)(l * 2 + 0) * 128 * DD;
        const float* gW1 = gW + (size_t)(l * 2 + 1) * 128 * DD;
        const float* gb0 = gb + (size_t)(l * 2 + 0) * DD;
        const float* gb1 = gb + (size_t)(l * 2 + 1) * DD;
        float* st1 = stats + l * 128;
        float* st2 = stats + l * 128 + 64;
        const float* pstats = (l == 0) ? nullptr : stats + 64;
        const float* pg = (l == 0) ? nullptr : bn2g;
        const float* pb = (l == 0) ? nullptr : bn2b;
        const float* gsrc = (l == 0) ? xt : t2n;
        const float* xres = (l == 0) ? xb : hB;

        k_gnn1<<<NN * 2, 256, 0, stream>>>(gsrc, hA, cnt_f, csr_off, csr_src, gW0, gb0,
                                           pstats, pg, pb);
        k_gnn2<<<NN * 2, 256, 0, stream>>>(hA, cnt_f, csr_off, csr_src, gW1, gb1,
                                           gsrc, pstats, pg, pb,
                                           Wq + l * DD * DD, Wk + l * DD * DD, Wv + l * DD * DD,
                                           qb2, kb2, vb2);
        k_attn_proj<<<BB * 8, 256, 0, stream>>>(qb2, kb2, vb2, xres, pstats, pg, pb,
                                                Wo + l * DD * DD, tb, st1);
        k_ff<<<512, 256, 0, stream>>>(tb, st1, bn1g + l * DD, bn1b + l * DD,
                                      fW1 + l * DD * FFD, fb1 + l * FFD,
                                      fW2 + l * FFD * DD, fb2 + l * DD,
                                      hB, (l == 0) ? t2n : nullptr, st2);
    }
    k_out<<<512, 256, 0, stream>>>(hB, stats + 192, bn2g + DD, bn2b + DD, oW, obv, out);
}